// Round 1
// baseline (4557.741 us; speedup 1.0000x reference)
//
#include <hip/hip_runtime.h>
#include <math.h>

#define T_ 128
#define B_ 32
#define V_ 32000
#define E_ 32
#define H_ 16

// ws layout (floats):
//   xw         [2][T][B][H]   offset      0, 131072 floats
//   feats      [T][B][2H]     offset 131072, 131072 floats
//   stats_part [T*B][4]       offset 262144,  16384 floats
//   lse        [T*B]          offset 278528,   4096 floats
// total ~1.13 MB

// Kernel 0: input contribution xw[dir][t][b][j] = b_ih[j] + emb[ix[t][b]] @ W[0:E, j]
__global__ __launch_bounds__(256) void xw_kernel(const int* __restrict__ ix,
                                                 const float* __restrict__ emb,
                                                 const float* __restrict__ W_lr,
                                                 const float* __restrict__ b_lr,
                                                 const float* __restrict__ W_rl,
                                                 const float* __restrict__ b_rl,
                                                 float* __restrict__ xw) {
    int idx = blockIdx.x * 256 + threadIdx.x;          // 131072 total
    int j = idx & 15;
    int b = (idx >> 4) & 31;
    int t = (idx >> 9) & 127;
    int dir = idx >> 16;
    const float* W    = dir ? W_rl : W_lr;
    const float* bias = dir ? b_rl : b_lr;
    int tok = ix[t * B_ + b];
    const float* er = emb + (long)tok * E_;
    float acc = bias[j];
#pragma unroll
    for (int e = 0; e < E_; ++e) acc += er[e] * W[e * H_ + j];
    xw[idx] = acc;
}

// Kernel 1: the two sequential scans. One block per direction, 512 threads = (b,j).
// h lives in LDS; W_h column in registers. Writes feats[t][b][0:16]=hLR[t],
// feats[t][b][16:32]=hRL[t+1].
__global__ __launch_bounds__(512) void scan_kernel(const float* __restrict__ xw,
                                                   const float* __restrict__ W_lr,
                                                   const float* __restrict__ W_rl,
                                                   const float* __restrict__ h0p,
                                                   const float* __restrict__ mask_lr,
                                                   const float* __restrict__ mask_rl,
                                                   float* __restrict__ feats) {
    int dir = blockIdx.x;
    int tid = threadIdx.x;
    int b = tid >> 4, j = tid & 15;
    const float* W    = dir ? W_rl : W_lr;
    const float* mask = dir ? mask_rl : mask_lr;
    const float* xwd  = xw + dir * (T_ * B_ * H_);
    float Wh[16];
#pragma unroll
    for (int k = 0; k < 16; ++k) Wh[k] = W[(E_ + k) * H_ + j];
    __shared__ float hs[32][16];
    float h0j = h0p[j];
    hs[b][j] = h0j;
    // boundary features: featL[0] = h0, featR[T-1] = h0
    if (dir == 0) feats[(0 * B_ + b) * 32 + j] = h0j;
    else          feats[((T_ - 1) * B_ + b) * 32 + 16 + j] = h0j;
    __syncthreads();
    for (int t = 0; t < T_; ++t) {
        int tt = dir ? (T_ - 1 - t) : t;   // token position consumed this step
        float acc = xwd[tt * (B_ * H_) + tid];
        const float4* h4 = (const float4*)(&hs[b][0]);
#pragma unroll
        for (int kk = 0; kk < 4; ++kk) {
            float4 hv = h4[kk];
            acc += hv.x * Wh[4 * kk] + hv.y * Wh[4 * kk + 1] +
                   hv.z * Wh[4 * kk + 2] + hv.w * Wh[4 * kk + 3];
        }
        float hn = tanhf(acc) * mask[tt * (B_ * H_) + tid];
        __syncthreads();
        hs[b][j] = hn;
        __syncthreads();
        if (t < T_ - 1) {
            // dir0: hn = hLR[t+1] -> feat position t+1 (left half)
            // dir1: hn = hRL[T-1-t] -> feat position T-2-t (right half)
            int p = dir ? (T_ - 2 - t) : (t + 1);
            feats[(p * B_ + b) * 32 + dir * 16 + j] = hn;
        }
    }
}

// Kernel 2: per-row sum(exp(logit)) partials. Block = 32 rows x 1 V-segment.
// Each thread owns one column per 256-wide tile, keeps 32 row-accumulators.
__global__ __launch_bounds__(256) void stats_kernel(const float* __restrict__ feats,
                                                    const float* __restrict__ W_ho,
                                                    const float* __restrict__ b_ho,
                                                    float* __restrict__ stats_part) {
    int rb = blockIdx.x;    // 0..127 (row tile)
    int sg = blockIdx.y;    // 0..3  (V segment of 8192; last = 7424)
    int tid = threadIdx.x;
    __shared__ float featS[32 * 32];
    __shared__ float part[4][32];
    for (int i = tid; i < 1024; i += 256) featS[i] = feats[rb * 1024 + i];
    __syncthreads();
    int ntiles = (sg == 3) ? 29 : 32;
    float s_acc[32];
#pragma unroll
    for (int r = 0; r < 32; ++r) s_acc[r] = 0.f;
    for (int tile = 0; tile < ntiles; ++tile) {
        int c = sg * 8192 + tile * 256 + tid;    // always < 32000 by construction
        float Wc[32];
#pragma unroll
        for (int k = 0; k < 32; ++k) Wc[k] = W_ho[k * V_ + c];
        float bc = b_ho[c];
#pragma unroll
        for (int r = 0; r < 32; ++r) {
            const float4* f4 = (const float4*)(featS + r * 32);
            float acc = bc;
#pragma unroll
            for (int kk = 0; kk < 8; ++kk) {
                float4 fv = f4[kk];
                acc += fv.x * Wc[4 * kk] + fv.y * Wc[4 * kk + 1] +
                       fv.z * Wc[4 * kk + 2] + fv.w * Wc[4 * kk + 3];
            }
            s_acc[r] += expf(acc);   // |logit| <= 10.25 -> no max subtraction needed
        }
    }
    int lane = tid & 63, wv = tid >> 6;
#pragma unroll
    for (int r = 0; r < 32; ++r) {
        float v = s_acc[r];
        for (int off = 32; off > 0; off >>= 1) v += __shfl_down(v, off, 64);
        if (lane == 0) part[wv][r] = v;
    }
    __syncthreads();
    if (tid < 32) {
        float S = part[0][tid] + part[1][tid] + part[2][tid] + part[3][tid];
        stats_part[(rb * 32 + tid) * 4 + sg] = S;
    }
}

// Kernel 2b: lse[row] = log(sum of 4 segment partials)
__global__ __launch_bounds__(256) void lse_kernel(const float* __restrict__ stats_part,
                                                  float* __restrict__ lse) {
    int r = blockIdx.x * 256 + threadIdx.x;
    if (r < T_ * B_) {
        float4 p = ((const float4*)stats_part)[r];
        lse[r] = logf(p.x + p.y + p.z + p.w);
    }
}

// Kernel 3: recompute logits and write out = logit - lse. Block = 32 rows x 256 cols.
__global__ __launch_bounds__(256) void out_kernel(const float* __restrict__ feats,
                                                  const float* __restrict__ W_ho,
                                                  const float* __restrict__ b_ho,
                                                  const float* __restrict__ lse,
                                                  float* __restrict__ out) {
    int ct = blockIdx.x;    // 0..124
    int rb = blockIdx.y;    // 0..127
    int tid = threadIdx.x;
    __shared__ float featS[1024];
    __shared__ float lseS[32];
    for (int i = tid; i < 1024; i += 256) featS[i] = feats[rb * 1024 + i];
    if (tid < 32) lseS[tid] = lse[rb * 32 + tid];
    __syncthreads();
    int c = ct * 256 + tid;                 // 125*256 = 32000 exactly
    float Wc[32];
#pragma unroll
    for (int k = 0; k < 32; ++k) Wc[k] = W_ho[k * V_ + c];
    float bc = b_ho[c];
#pragma unroll
    for (int r = 0; r < 32; ++r) {
        const float4* f4 = (const float4*)(featS + r * 32);
        float acc = bc;
#pragma unroll
        for (int kk = 0; kk < 8; ++kk) {
            float4 fv = f4[kk];
            acc += fv.x * Wc[4 * kk] + fv.y * Wc[4 * kk + 1] +
                   fv.z * Wc[4 * kk + 2] + fv.w * Wc[4 * kk + 3];
        }
        out[(rb * 32 + r) * V_ + c] = acc - lseS[r];
    }
}

extern "C" void kernel_launch(void* const* d_in, const int* in_sizes, int n_in,
                              void* d_out, int out_size, void* d_ws, size_t ws_size,
                              hipStream_t stream) {
    const int*   ix      = (const int*)d_in[0];
    const float* emb     = (const float*)d_in[1];
    const float* W_lr    = (const float*)d_in[2];
    const float* b_lr    = (const float*)d_in[3];
    const float* W_rl    = (const float*)d_in[4];
    const float* b_rl    = (const float*)d_in[5];
    const float* W_ho    = (const float*)d_in[6];
    const float* b_ho    = (const float*)d_in[7];
    const float* h0      = (const float*)d_in[8];
    const float* mask_lr = (const float*)d_in[9];
    const float* mask_rl = (const float*)d_in[10];
    float* out = (float*)d_out;
    float* ws  = (float*)d_ws;

    float* xw         = ws;                 // 131072
    float* feats      = ws + 131072;        // 131072
    float* stats_part = ws + 262144;        //  16384
    float* lse        = ws + 278528;        //   4096

    xw_kernel<<<512, 256, 0, stream>>>(ix, emb, W_lr, b_lr, W_rl, b_rl, xw);
    scan_kernel<<<2, 512, 0, stream>>>(xw, W_lr, W_rl, h0, mask_lr, mask_rl, feats);
    stats_kernel<<<dim3(128, 4), 256, 0, stream>>>(feats, W_ho, b_ho, stats_part);
    lse_kernel<<<16, 256, 0, stream>>>(stats_part, lse);
    out_kernel<<<dim3(125, 128), 256, 0, stream>>>(feats, W_ho, b_ho, lse, out);
}

// Round 2
// 847.314 us; speedup vs baseline: 5.3790x; 5.3790x over previous
//
#include <hip/hip_runtime.h>
#include <math.h>

#define T_ 128
#define B_ 32
#define V_ 32000
#define E_ 32
#define H_ 16

// ws layout (floats):
//   xw         [2][T][B][H]   offset      0, 131072 floats
//   feats      [T][B][2H]     offset 131072, 131072 floats
//   stats_part [T*B][4]       offset 262144,  16384 floats
//   lse        [T*B]          offset 278528,   4096 floats

// Kernel 0: input contribution xw[dir][t][b][j] = b_ih[j] + emb[ix[t][b]] @ W[0:E, j]
__global__ __launch_bounds__(256) void xw_kernel(const int* __restrict__ ix,
                                                 const float* __restrict__ emb,
                                                 const float* __restrict__ W_lr,
                                                 const float* __restrict__ b_lr,
                                                 const float* __restrict__ W_rl,
                                                 const float* __restrict__ b_rl,
                                                 float* __restrict__ xw) {
    int idx = blockIdx.x * 256 + threadIdx.x;          // 131072 total
    int j = idx & 15;
    int b = (idx >> 4) & 31;
    int t = (idx >> 9) & 127;
    int dir = idx >> 16;
    const float* W    = dir ? W_rl : W_lr;
    const float* bias = dir ? b_rl : b_lr;
    int tok = ix[t * B_ + b];
    const float* er = emb + (long)tok * E_;
    float acc = bias[j];
#pragma unroll
    for (int e = 0; e < E_; ++e) acc += er[e] * W[e * H_ + j];
    xw[idx] = acc;
}

// Kernel 1: the two sequential scans. One block per direction, 512 threads = (b,j).
__global__ __launch_bounds__(512) void scan_kernel(const float* __restrict__ xw,
                                                   const float* __restrict__ W_lr,
                                                   const float* __restrict__ W_rl,
                                                   const float* __restrict__ h0p,
                                                   const float* __restrict__ mask_lr,
                                                   const float* __restrict__ mask_rl,
                                                   float* __restrict__ feats) {
    int dir = blockIdx.x;
    int tid = threadIdx.x;
    int b = tid >> 4, j = tid & 15;
    const float* W    = dir ? W_rl : W_lr;
    const float* mask = dir ? mask_rl : mask_lr;
    const float* xwd  = xw + dir * (T_ * B_ * H_);
    float Wh[16];
#pragma unroll
    for (int k = 0; k < 16; ++k) Wh[k] = W[(E_ + k) * H_ + j];
    __shared__ float hs[32][16];
    float h0j = h0p[j];
    hs[b][j] = h0j;
    if (dir == 0) feats[(0 * B_ + b) * 32 + j] = h0j;
    else          feats[((T_ - 1) * B_ + b) * 32 + 16 + j] = h0j;
    __syncthreads();
    for (int t = 0; t < T_; ++t) {
        int tt = dir ? (T_ - 1 - t) : t;   // token position consumed this step
        float acc = xwd[tt * (B_ * H_) + tid];
        const float4* h4 = (const float4*)(&hs[b][0]);
#pragma unroll
        for (int kk = 0; kk < 4; ++kk) {
            float4 hv = h4[kk];
            acc += hv.x * Wh[4 * kk] + hv.y * Wh[4 * kk + 1] +
                   hv.z * Wh[4 * kk + 2] + hv.w * Wh[4 * kk + 3];
        }
        float hn = tanhf(acc) * mask[tt * (B_ * H_) + tid];
        __syncthreads();
        hs[b][j] = hn;
        __syncthreads();
        if (t < T_ - 1) {
            int p = dir ? (T_ - 2 - t) : (t + 1);
            feats[(p * B_ + b) * 32 + dir * 16 + j] = hn;
        }
    }
}

// Kernel 2: per-row sum(exp(logit)) partials. Block = 16 rows x 1 V-segment.
// 16 rows/block keeps s_acc[16]+Wc[32] well under the VGPR spill cliff.
__global__ __launch_bounds__(256) void stats_kernel(const float* __restrict__ feats,
                                                    const float* __restrict__ W_ho,
                                                    const float* __restrict__ b_ho,
                                                    float* __restrict__ stats_part) {
    int rb = blockIdx.x;    // 0..255 (row tile of 16)
    int sg = blockIdx.y;    // 0..3  (V segment of 8192; last = 7424)
    int tid = threadIdx.x;
    __shared__ float featS[16 * 32];
    __shared__ float part[4][16];
    for (int i = tid; i < 512; i += 256) featS[i] = feats[rb * 512 + i];
    __syncthreads();
    int ntiles = (sg == 3) ? 29 : 32;
    float s_acc[16];
#pragma unroll
    for (int r = 0; r < 16; ++r) s_acc[r] = 0.f;
#pragma unroll 1
    for (int tile = 0; tile < ntiles; ++tile) {
        int c = sg * 8192 + tile * 256 + tid;    // always < 32000 by construction
        float Wc[32];
#pragma unroll
        for (int k = 0; k < 32; ++k) Wc[k] = W_ho[k * V_ + c];
        float bc = b_ho[c];
#pragma unroll
        for (int r = 0; r < 16; ++r) {
            const float4* f4 = (const float4*)(featS + r * 32);
            float acc = bc;
#pragma unroll
            for (int kk = 0; kk < 8; ++kk) {
                float4 fv = f4[kk];
                acc += fv.x * Wc[4 * kk] + fv.y * Wc[4 * kk + 1] +
                       fv.z * Wc[4 * kk + 2] + fv.w * Wc[4 * kk + 3];
            }
            s_acc[r] += __expf(acc);   // |logit| <= 10.25 -> no max subtraction needed
        }
    }
    int lane = tid & 63, wv = tid >> 6;
#pragma unroll
    for (int r = 0; r < 16; ++r) {
        float v = s_acc[r];
        for (int off = 32; off > 0; off >>= 1) v += __shfl_down(v, off, 64);
        if (lane == 0) part[wv][r] = v;
    }
    __syncthreads();
    if (tid < 16) {
        float S = part[0][tid] + part[1][tid] + part[2][tid] + part[3][tid];
        stats_part[(rb * 16 + tid) * 4 + sg] = S;
    }
}

// Kernel 2b: lse[row] = log(sum of 4 segment partials)
__global__ __launch_bounds__(256) void lse_kernel(const float* __restrict__ stats_part,
                                                  float* __restrict__ lse) {
    int r = blockIdx.x * 256 + threadIdx.x;
    if (r < T_ * B_) {
        float4 p = ((const float4*)stats_part)[r];
        lse[r] = __logf(p.x + p.y + p.z + p.w);
    }
}

// Kernel 3: recompute logits and write out = logit - lse. Block = 16 rows x 256 cols.
// blockIdx.x = row tile so consecutive blocks reuse the same W_ho slice in L2.
__global__ __launch_bounds__(256) void out_kernel(const float* __restrict__ feats,
                                                  const float* __restrict__ W_ho,
                                                  const float* __restrict__ b_ho,
                                                  const float* __restrict__ lse,
                                                  float* __restrict__ out) {
    int rb = blockIdx.x;    // 0..255 (row tile of 16)
    int ct = blockIdx.y;    // 0..124
    int tid = threadIdx.x;
    __shared__ float featS[512];
    __shared__ float lseS[16];
    for (int i = tid; i < 512; i += 256) featS[i] = feats[rb * 512 + i];
    if (tid < 16) lseS[tid] = lse[rb * 16 + tid];
    __syncthreads();
    int c = ct * 256 + tid;                 // 125*256 = 32000 exactly
    float Wc[32];
#pragma unroll
    for (int k = 0; k < 32; ++k) Wc[k] = W_ho[k * V_ + c];
    float bc = b_ho[c];
#pragma unroll
    for (int r = 0; r < 16; ++r) {
        const float4* f4 = (const float4*)(featS + r * 32);
        float acc = bc;
#pragma unroll
        for (int kk = 0; kk < 8; ++kk) {
            float4 fv = f4[kk];
            acc += fv.x * Wc[4 * kk] + fv.y * Wc[4 * kk + 1] +
                   fv.z * Wc[4 * kk + 2] + fv.w * Wc[4 * kk + 3];
        }
        out[(rb * 16 + r) * V_ + c] = acc - lseS[r];
    }
}

extern "C" void kernel_launch(void* const* d_in, const int* in_sizes, int n_in,
                              void* d_out, int out_size, void* d_ws, size_t ws_size,
                              hipStream_t stream) {
    const int*   ix      = (const int*)d_in[0];
    const float* emb     = (const float*)d_in[1];
    const float* W_lr    = (const float*)d_in[2];
    const float* b_lr    = (const float*)d_in[3];
    const float* W_rl    = (const float*)d_in[4];
    const float* b_rl    = (const float*)d_in[5];
    const float* W_ho    = (const float*)d_in[6];
    const float* b_ho    = (const float*)d_in[7];
    const float* h0      = (const float*)d_in[8];
    const float* mask_lr = (const float*)d_in[9];
    const float* mask_rl = (const float*)d_in[10];
    float* out = (float*)d_out;
    float* ws  = (float*)d_ws;

    float* xw         = ws;                 // 131072
    float* feats      = ws + 131072;        // 131072
    float* stats_part = ws + 262144;        //  16384
    float* lse        = ws + 278528;        //   4096

    xw_kernel<<<512, 256, 0, stream>>>(ix, emb, W_lr, b_lr, W_rl, b_rl, xw);
    scan_kernel<<<2, 512, 0, stream>>>(xw, W_lr, W_rl, h0, mask_lr, mask_rl, feats);
    stats_kernel<<<dim3(256, 4), 256, 0, stream>>>(feats, W_ho, b_ho, stats_part);
    lse_kernel<<<16, 256, 0, stream>>>(stats_part, lse);
    out_kernel<<<dim3(256, 125), 256, 0, stream>>>(feats, W_ho, b_ho, lse, out);
}